// Round 9
// baseline (93.550 us; speedup 1.0000x reference)
//
#include <hip/hip_runtime.h>
#include <hip/hip_bf16.h>

#define LL 50
#define DD 64
#define NCATS 1000
#define NRAT 5

// ws byte offsets
#define OFF_H    0          // ushort[1000*5*64] = 640000 B (bf16 H table)
#define OFF_M1T  640000     // ushort[64*64] bf16 (M1t[d][e] = (Wq Wk^T)[e][d])
#define OFF_WVOT 648192     // ushort[64*64] bf16 (Wvot[d][e] = (Wv Wo)[e][d])
#define OFF_BKQ  656384     // float[64]  (Wk @ bq)
#define OFF_BVO  656640     // float[64]  (bv @ Wo + bo)

typedef __attribute__((ext_vector_type(8))) short short8;
typedef __attribute__((ext_vector_type(4))) float f32x4;

union U4S8 { uint4 u4; short8 s8; };

__device__ __forceinline__ float rlanef(float v, int l) {
  return __uint_as_float(__builtin_amdgcn_readlane(__float_as_uint(v), l));
}
__device__ __forceinline__ unsigned short f2bf(float f) {  // RNE f32->bf16
  unsigned int u = __float_as_uint(f);
  u = (u + 0x7fffu + ((u >> 16) & 1u)) >> 16;
  return (unsigned short)u;
}
__device__ __forceinline__ unsigned int pk2bf(float lo, float hi) {
  return (unsigned int)f2bf(lo) | ((unsigned int)f2bf(hi) << 16);
}

// ---------------- prep: all tables, one kernel, independent 1-wave blocks ----------------
__global__ __launch_bounds__(64) void prep_kernel(
    const float* __restrict__ c2e, const float* __restrict__ r2e,
    const float* __restrict__ W1, const float* __restrict__ b1,
    const float* __restrict__ Wq, const float* __restrict__ bq,
    const float* __restrict__ Wk, const float* __restrict__ Wv,
    const float* __restrict__ Wo, const float* __restrict__ bv,
    const float* __restrict__ bo, char* __restrict__ ws) {
  const int lane = threadIdx.x;
  const int b = blockIdx.x;
  unsigned short* H = (unsigned short*)(ws + OFF_H);
  unsigned short* M1T = (unsigned short*)(ws + OFF_M1T);
  unsigned short* WVOT = (unsigned short*)(ws + OFF_WVOT);
  float* BKQ = (float*)(ws + OFF_BKQ);
  float* BVO = (float*)(ws + OFF_BVO);

  if (b < NCATS) {
    const int vc = b;
    const float* __restrict__ crow = c2e + (size_t)vc * DD;
    float av = 0.f;
#pragma unroll 8
    for (int e = 0; e < DD; ++e) av = fmaf(crow[e], W1[e * DD + lane], av);
#pragma unroll
    for (int r = 0; r < NRAT; ++r) {
      const float* __restrict__ rrow = r2e + (size_t)r * DD;
      float hb = b1[lane];
#pragma unroll 8
      for (int e = 0; e < DD; ++e) hb = fmaf(rrow[e], W1[(DD + e) * DD + lane], hb);
      H[((size_t)vc * NRAT + r) * DD + lane] = f2bf(fmaxf(av + hb, 0.f));
    }
  } else if (b < 1064) {
    const int d = b - 1000;
    float acc = 0.f;
#pragma unroll 8
    for (int t = 0; t < DD; ++t) acc = fmaf(Wq[lane * DD + t], Wk[d * DD + t], acc);
    M1T[d * DD + lane] = f2bf(acc);
  } else if (b < 1128) {
    const int d = b - 1064;
    float acc = 0.f;
#pragma unroll 8
    for (int t = 0; t < DD; ++t) acc = fmaf(Wv[lane * DD + t], Wo[t * DD + d], acc);
    WVOT[d * DD + lane] = f2bf(acc);
  } else {
    float a1 = 0.f, a2 = bo[lane];
#pragma unroll 8
    for (int t = 0; t < DD; ++t) {
      a1 = fmaf(Wk[lane * DD + t], bq[t], a1);
      a2 = fmaf(bv[t], Wo[t * DD + lane], a2);
    }
    BKQ[lane] = a1;
    BVO[lane] = a2;
  }
}

// ---------------- main: 256 threads, 4 nodes per block, 1 node per wave ----------------
// IDENTICAL to round 8. Launched 3x this round to split prep vs main timing:
// main = (dur9 - dur8)/2, prep = dur8 - main. vc_main is idempotent (pure
// overwrite of out from ws/inputs), so repeated launches are safe.
__global__ __launch_bounds__(256, 5) void vc_main(
    const int* __restrict__ nodes, const int* __restrict__ hvc,
    const int* __restrict__ hr, const float* __restrict__ v2e,
    const char* __restrict__ ws, float* __restrict__ out, int N) {
  const unsigned short* __restrict__ H = (const unsigned short*)(ws + OFF_H);
  const unsigned short* __restrict__ M1T = (const unsigned short*)(ws + OFF_M1T);
  const unsigned short* __restrict__ WVOT = (const unsigned short*)(ws + OFF_WVOT);
  const float* __restrict__ BKQ = (const float*)(ws + OFF_BKQ);
  const float* __restrict__ BVO = (const float*)(ws + OFF_BVO);

  __shared__ __align__(16) char smem[25600 + 1088 + 1088];
  char* HlB = smem;                          // 4 waves x 50 rows x 128B, swizzled
  float* gS = (float*)(smem + 25600);        // [4][68] f32
  float* ctxS = (float*)(smem + 25600 + 1088);  // [4][68] f32

  const int tid = threadIdx.x;
  const int wid = tid >> 6;    // 0..3  (= node within block, = d-quarter n0)
  const int lane = tid & 63;
  const int kg = lane >> 4;    // 0..3
  const int rw = lane & 15;    // 0..15
  const int nb = blockIdx.x * 4;
  const int n = min(nb + wid, N - 1);

  // ---- history indices: lane l <-> slot l ----
  const int lidx = (lane < LL) ? lane : 0;
  const int idx = hvc[(size_t)n * LL + lidx] * NRAT + hr[(size_t)n * LL + lidx];

  // ---- async stage: 7 x global_load_lds, each = 8 rows (64 lanes x 16B) ----
  {
    const int chunk = lane & 7;
    char* wbase = HlB + wid * 6400;
#pragma unroll
    for (int i = 0; i < 7; ++i) {
      const int s = (i < 6) ? (i * 8 + (lane >> 3)) : (42 + (lane >> 3));
      const int sidx = __shfl(idx, s, 64);
      const char* src = (const char*)H + (size_t)sidx * 128 + ((chunk ^ (s & 7)) << 4);
      __builtin_amdgcn_global_load_lds(
          (const __attribute__((address_space(1))) void*)src,
          (__attribute__((address_space(3))) void*)(wbase + ((i < 6) ? i * 1024 : 5376)),
          16, 0, 0);
    }
  }

  // ---- G = X @ M1 + bkq : wave wid computes d-quarter n0==wid for the 4 nodes ----
  {
    const int node_id = nodes[min(nb + (rw & 3), N - 1)];
    const float* __restrict__ xrow = v2e + (size_t)node_id * DD;
    short8 xa[2];
#pragma unroll
    for (int ks = 0; ks < 2; ++ks) {
      const float4 f0 = *(const float4*)(xrow + ks * 32 + kg * 8);
      const float4 f1 = *(const float4*)(xrow + ks * 32 + kg * 8 + 4);
      U4S8 t;
      t.u4.x = pk2bf(f0.x, f0.y); t.u4.y = pk2bf(f0.z, f0.w);
      t.u4.z = pk2bf(f1.x, f1.y); t.u4.w = pk2bf(f1.z, f1.w);
      xa[ks] = t.s8;
    }
    const int n0 = wid;
    f32x4 a = {0.f, 0.f, 0.f, 0.f};
#pragma unroll
    for (int ks = 0; ks < 2; ++ks) {
      const short8 bf = *(const short8*)(M1T + (n0 * 16 + rw) * DD + ks * 32 + kg * 8);
      a = __builtin_amdgcn_mfma_f32_16x16x32_bf16(xa[ks], bf, a, 0, 0, 0);
    }
    if (kg == 0) {   // C rows 0..3 = nodes 0..3
      const float bkqv = BKQ[n0 * 16 + rw];
#pragma unroll
      for (int r = 0; r < 4; ++r) gS[r * 68 + n0 * 16 + rw] = a[r] + bkqv;
    }
  }
  __syncthreads();
  asm volatile("s_waitcnt vmcnt(0)" ::: "memory");  // H-stage complete
  __builtin_amdgcn_sched_barrier(0);

  const unsigned short* __restrict__ wH = (const unsigned short*)(HlB + wid * 6400);

  // ---- scores via MFMA from LDS ----
  short8 ga[2];
#pragma unroll
  for (int ks = 0; ks < 2; ++ks) {
    const float* __restrict__ gp = gS + wid * 68 + ks * 32 + kg * 8;
    const float4 f0 = *(const float4*)(gp);
    const float4 f1 = *(const float4*)(gp + 4);
    U4S8 t;
    t.u4.x = pk2bf(f0.x, f0.y); t.u4.y = pk2bf(f0.z, f0.w);
    t.u4.z = pk2bf(f1.x, f1.y); t.u4.w = pk2bf(f1.z, f1.w);
    ga[ks] = t.s8;
  }
  float s0, s1, s2, s3;
  {
    f32x4 a;
#pragma unroll
    for (int lt = 0; lt < 4; ++lt) {
      const int s = lt * 16 + rw;
      a = (f32x4){0.f, 0.f, 0.f, 0.f};
#pragma unroll
      for (int ks = 0; ks < 2; ++ks) {
        const int c = (ks * 4 + kg) ^ (s & 7);
        U4S8 hb;
        hb.u4 = *(const uint4*)(wH + s * 64 + c * 8);
        a = __builtin_amdgcn_mfma_f32_16x16x32_bf16(ga[ks], hb.s8, a, 0, 0, 0);
      }
      if (lt == 0) s0 = a[0];
      else if (lt == 1) s1 = a[0];
      else if (lt == 2) s2 = a[0];
      else s3 = a[0];
    }
  }
  s0 *= 0.125f; s1 *= 0.125f; s2 *= 0.125f;
  s3 = (rw < 2) ? s3 * 0.125f : -INFINITY;

  // ---- softmax over 50 slots ----
  float m = fmaxf(fmaxf(s0, s1), fmaxf(s2, s3));
#pragma unroll
  for (int x = 1; x <= 8; x <<= 1) m = fmaxf(m, __shfl_xor(m, x, 64));
  float e0 = __expf(s0 - m), e1 = __expf(s1 - m), e2 = __expf(s2 - m);
  float e3 = (rw < 2) ? __expf(s3 - m) : 0.f;
  float Z = ((e0 + e1) + (e2 + e3));
#pragma unroll
  for (int x = 1; x <= 8; x <<= 1) Z += __shfl_xor(Z, x, 64);
  const float invZ = 1.f / Z;

  // ---- ctx[d=lane] = sum_l e_l * H[slot l][d] / Z, all from LDS ----
  {
    const int sub = (lane & 7) * 2;
    const int hi3 = lane >> 3;
    float c0 = 0.f, c1 = 0.f;
#define CTX_BLOCK(EREG, BASE, CNT, CACC)                                        \
    _Pragma("unroll")                                                           \
    for (int j = 0; j < (CNT); ++j) {                                           \
      const int l = (BASE) + j;                                                 \
      const unsigned short hbb = *(const unsigned short*)(                      \
          (const char*)wH + l * 128 + (((hi3 ^ (l & 7)) << 4) | sub));          \
      CACC = fmaf(__uint_as_float(((unsigned int)hbb) << 16),                   \
                  rlanef(EREG, j), CACC);                                       \
    }
    CTX_BLOCK(e0, 0, 16, c0)
    CTX_BLOCK(e1, 16, 16, c1)
    CTX_BLOCK(e2, 32, 16, c0)
    CTX_BLOCK(e3, 48, 2, c1)
#undef CTX_BLOCK
    ctxS[wid * 68 + lane] = (c0 + c1) * invZ;
  }
  __syncthreads();

  // ---- OUT = CTX @ Wvo + bvo : wave wid computes d-quarter n0==wid ----
  {
    short8 ca[2];
#pragma unroll
    for (int ks = 0; ks < 2; ++ks) {
      const float* __restrict__ cp = ctxS + (rw & 3) * 68 + ks * 32 + kg * 8;
      const float4 f0 = *(const float4*)(cp);
      const float4 f1 = *(const float4*)(cp + 4);
      U4S8 t;
      t.u4.x = pk2bf(f0.x, f0.y); t.u4.y = pk2bf(f0.z, f0.w);
      t.u4.z = pk2bf(f1.x, f1.y); t.u4.w = pk2bf(f1.z, f1.w);
      ca[ks] = t.s8;
    }
    const int n0 = wid;
    f32x4 a = {0.f, 0.f, 0.f, 0.f};
#pragma unroll
    for (int ks = 0; ks < 2; ++ks) {
      const short8 bf = *(const short8*)(WVOT + (n0 * 16 + rw) * DD + ks * 32 + kg * 8);
      a = __builtin_amdgcn_mfma_f32_16x16x32_bf16(ca[ks], bf, a, 0, 0, 0);
    }
    if (kg == 0) {
      const float bvov = BVO[n0 * 16 + rw];
#pragma unroll
      for (int r = 0; r < 4; ++r) {
        const int node = nb + r;
        if (node < N) out[(size_t)node * DD + n0 * 16 + rw] = a[r] + bvov;
      }
    }
  }
}

extern "C" void kernel_launch(void* const* d_in, const int* in_sizes, int n_in,
                              void* d_out, int out_size, void* d_ws, size_t ws_size,
                              hipStream_t stream) {
  const int* nodes = (const int*)d_in[0];
  const int* hvc = (const int*)d_in[1];
  const int* hr = (const int*)d_in[2];
  const float* c2e = (const float*)d_in[3];
  const float* v2e = (const float*)d_in[4];
  const float* r2e = (const float*)d_in[5];
  const float* W1 = (const float*)d_in[6];
  const float* b1 = (const float*)d_in[7];
  const float* Wq = (const float*)d_in[8];
  const float* bq = (const float*)d_in[9];
  const float* Wk = (const float*)d_in[10];
  const float* bk = (const float*)d_in[11];  // unused: q·bk cancels in softmax
  const float* Wv = (const float*)d_in[12];
  const float* bv = (const float*)d_in[13];
  const float* Wo = (const float*)d_in[14];
  const float* bo = (const float*)d_in[15];
  (void)bk;
  float* out = (float*)d_out;
  char* ws = (char*)d_ws;

  const int N = in_sizes[0];

  prep_kernel<<<1129, 64, 0, stream>>>(c2e, r2e, W1, b1, Wq, bq, Wk, Wv, Wo, bv, bo, ws);
  // Measurement round: vc_main launched 3x (idempotent). main = (dur9-dur8)/2.
  vc_main<<<(N + 3) / 4, 256, 0, stream>>>(nodes, hvc, hr, v2e, ws, out, N);
  vc_main<<<(N + 3) / 4, 256, 0, stream>>>(nodes, hvc, hr, v2e, ws, out, N);
  vc_main<<<(N + 3) / 4, 256, 0, stream>>>(nodes, hvc, hr, v2e, ws, out, N);
}

// Round 10
// 36.572 us; speedup vs baseline: 2.5580x; 2.5580x over previous
//
#include <hip/hip_runtime.h>
#include <hip/hip_bf16.h>

#define LL 50
#define DD 64
#define NCATS 1000
#define NRAT 5

// ws byte offsets
#define OFF_H    0          // ushort[1000*5*64] = 640000 B (bf16 H table)
#define OFF_M1T  640000     // ushort[64*64] bf16 (M1t[d][e] = (Wq Wk^T)[e][d])
#define OFF_WVOT 648192     // ushort[64*64] bf16 (Wvot[d][e] = (Wv Wo)[e][d])
#define OFF_BKQ  656384     // float[64]  (Wk @ bq)
#define OFF_BVO  656640     // float[64]  (bv @ Wo + bo)

typedef __attribute__((ext_vector_type(8))) short short8;
typedef __attribute__((ext_vector_type(4))) float f32x4;

union U4S8 { uint4 u4; short8 s8; };

__device__ __forceinline__ float rlanef(float v, int l) {
  return __uint_as_float(__builtin_amdgcn_readlane(__float_as_uint(v), l));
}
__device__ __forceinline__ unsigned short f2bf(float f) {  // RNE f32->bf16
  unsigned int u = __float_as_uint(f);
  u = (u + 0x7fffu + ((u >> 16) & 1u)) >> 16;
  return (unsigned short)u;
}
__device__ __forceinline__ unsigned int pk2bf(float lo, float hi) {
  return (unsigned int)f2bf(lo) | ((unsigned int)f2bf(hi) << 16);
}
__device__ __forceinline__ short8 pack8(float4 f0, float4 f1) {
  U4S8 t;
  t.u4.x = pk2bf(f0.x, f0.y); t.u4.y = pk2bf(f0.z, f0.w);
  t.u4.z = pk2bf(f1.x, f1.y); t.u4.w = pk2bf(f1.z, f1.w);
  return t.s8;
}

// ---------------- prep_fast: 65 blocks x 256 threads, MFMA tiles ----------------
//  b in [0,63): 16 rows of Ac = c2e@W1a (MFMA) + redundant Ar = r2e@W1b,
//               then assemble H[vc][r][d] = bf16(relu(Ac+Ar+b1)), coalesced.
//  b == 63:     M1T[d][e] = (Wq Wk^T)[e][d]  (MFMA)  + BKQ (wave 0, VALU)
//  b == 64:     WVOT[d][e] = (Wv@Wo)[e][d]   (MFMA)  + BVO (wave 0, VALU)
__global__ __launch_bounds__(256) void prep_fast(
    const float* __restrict__ c2e, const float* __restrict__ r2e,
    const float* __restrict__ W1, const float* __restrict__ b1,
    const float* __restrict__ Wq, const float* __restrict__ bq,
    const float* __restrict__ Wk, const float* __restrict__ Wv,
    const float* __restrict__ Wo, const float* __restrict__ bv,
    const float* __restrict__ bo, char* __restrict__ ws) {
  unsigned short* H = (unsigned short*)(ws + OFF_H);
  unsigned short* M1T = (unsigned short*)(ws + OFF_M1T);
  unsigned short* WVOT = (unsigned short*)(ws + OFF_WVOT);
  float* BKQ = (float*)(ws + OFF_BKQ);
  float* BVO = (float*)(ws + OFF_BVO);

  __shared__ float AcS[16][68];
  __shared__ float ArS[5][68];

  const int tid = threadIdx.x;
  const int wid = tid >> 6;
  const int lane = tid & 63;
  const int kg = lane >> 4;
  const int rw = lane & 15;
  const int b = blockIdx.x;

  if (b < 63) {
    // ---- A-frags: c2e row (this block's tile) and r2e row (rw<5) ----
    const int crow = min(b * 16 + rw, NCATS - 1);
    const float* __restrict__ xc = c2e + (size_t)crow * DD;
    const float* __restrict__ xr = r2e + (size_t)min(rw, NRAT - 1) * DD;
    short8 ac_[2], ar_[2], bfa[2], bfb[2];
#pragma unroll
    for (int ks = 0; ks < 2; ++ks) {
      const int k0 = ks * 32 + kg * 8;
      ac_[ks] = pack8(*(const float4*)(xc + k0), *(const float4*)(xc + k0 + 4));
      ar_[ks] = pack8(*(const float4*)(xr + k0), *(const float4*)(xr + k0 + 4));
      // B-frags: W1a / W1b column-tile n0==wid, strided dword reads
      U4S8 ta, tb;
#pragma unroll
      for (int j = 0; j < 4; ++j) {
        const int k = k0 + 2 * j;
        const int col = wid * 16 + rw;
        ((unsigned int*)&ta)[j] = pk2bf(W1[(size_t)k * DD + col],
                                        W1[(size_t)(k + 1) * DD + col]);
        ((unsigned int*)&tb)[j] = pk2bf(W1[(size_t)(DD + k) * DD + col],
                                        W1[(size_t)(DD + k + 1) * DD + col]);
      }
      bfa[ks] = ta.s8;
      bfb[ks] = tb.s8;
    }
    f32x4 accc = {0.f, 0.f, 0.f, 0.f}, accr = {0.f, 0.f, 0.f, 0.f};
#pragma unroll
    for (int ks = 0; ks < 2; ++ks) {
      accc = __builtin_amdgcn_mfma_f32_16x16x32_bf16(ac_[ks], bfa[ks], accc, 0, 0, 0);
      accr = __builtin_amdgcn_mfma_f32_16x16x32_bf16(ar_[ks], bfb[ks], accr, 0, 0, 0);
    }
#pragma unroll
    for (int r = 0; r < 4; ++r) {
      const int m = kg * 4 + r;                    // C row
      AcS[m][wid * 16 + rw] = accc[r];
      if (m < NRAT) ArS[m][wid * 16 + rw] = accr[r];
    }
    __syncthreads();

    // ---- assemble H: wave wid handles vc_local wid*4..+3, all 5 ratings ----
    const float b1v = b1[lane];
    float ar5[NRAT];
#pragma unroll
    for (int r = 0; r < NRAT; ++r) ar5[r] = ArS[r][lane] + b1v;
#pragma unroll
    for (int i = 0; i < 4; ++i) {
      const int vc = b * 16 + wid * 4 + i;
      if (vc < NCATS) {
        const float acv = AcS[wid * 4 + i][lane];
#pragma unroll
        for (int r = 0; r < NRAT; ++r) {
          H[((size_t)vc * NRAT + r) * DD + lane] = f2bf(fmaxf(acv + ar5[r], 0.f));
        }
      }
    }
  } else if (b == 63) {
    // ---- M1T: C[e][d] = Wq[e]·Wk[d]; wave wid = e-tile ----
    short8 aq[2];
#pragma unroll
    for (int ks = 0; ks < 2; ++ks) {
      const float* __restrict__ p = Wq + (size_t)(wid * 16 + rw) * DD + ks * 32 + kg * 8;
      aq[ks] = pack8(*(const float4*)(p), *(const float4*)(p + 4));
    }
#pragma unroll
    for (int n0 = 0; n0 < 4; ++n0) {
      f32x4 a = {0.f, 0.f, 0.f, 0.f};
#pragma unroll
      for (int ks = 0; ks < 2; ++ks) {
        const float* __restrict__ p = Wk + (size_t)(n0 * 16 + rw) * DD + ks * 32 + kg * 8;
        const short8 bf = pack8(*(const float4*)(p), *(const float4*)(p + 4));
        a = __builtin_amdgcn_mfma_f32_16x16x32_bf16(aq[ks], bf, a, 0, 0, 0);
      }
#pragma unroll
      for (int r = 0; r < 4; ++r) {
        // e = wid*16+kg*4+r, d = n0*16+rw ; M1T[d][e]
        M1T[(size_t)(n0 * 16 + rw) * DD + wid * 16 + kg * 4 + r] = f2bf(a[r]);
      }
    }
    if (wid == 0) {  // BKQ[d] = Wk[d]·bq
      const float* __restrict__ wrow = Wk + (size_t)lane * DD;
      float a0 = 0.f, a1 = 0.f, a2 = 0.f, a3 = 0.f;
#pragma unroll
      for (int t = 0; t < DD; t += 4) {
        const float4 w4 = *(const float4*)(wrow + t);
        a0 = fmaf(w4.x, bq[t + 0], a0);
        a1 = fmaf(w4.y, bq[t + 1], a1);
        a2 = fmaf(w4.z, bq[t + 2], a2);
        a3 = fmaf(w4.w, bq[t + 3], a3);
      }
      BKQ[lane] = (a0 + a1) + (a2 + a3);
    }
  } else {
    // ---- WVOT: C[d][e] = sum_t Wo[t][d]*Wv[e][t]; wave wid = d-tile ----
    short8 ao[2];
#pragma unroll
    for (int ks = 0; ks < 2; ++ks) {
      U4S8 t4;
#pragma unroll
      for (int j = 0; j < 4; ++j) {
        const int k = ks * 32 + kg * 8 + 2 * j;
        const int col = wid * 16 + rw;
        ((unsigned int*)&t4)[j] = pk2bf(Wo[(size_t)k * DD + col],
                                        Wo[(size_t)(k + 1) * DD + col]);
      }
      ao[ks] = t4.s8;
    }
#pragma unroll
    for (int n0 = 0; n0 < 4; ++n0) {
      f32x4 a = {0.f, 0.f, 0.f, 0.f};
#pragma unroll
      for (int ks = 0; ks < 2; ++ks) {
        const float* __restrict__ p = Wv + (size_t)(n0 * 16 + rw) * DD + ks * 32 + kg * 8;
        const short8 bf = pack8(*(const float4*)(p), *(const float4*)(p + 4));
        a = __builtin_amdgcn_mfma_f32_16x16x32_bf16(ao[ks], bf, a, 0, 0, 0);
      }
#pragma unroll
      for (int r = 0; r < 4; ++r) {
        // d = wid*16+kg*4+r, e = n0*16+rw ; WVOT[d][e]
        WVOT[(size_t)(wid * 16 + kg * 4 + r) * DD + n0 * 16 + rw] = f2bf(a[r]);
      }
    }
    if (wid == 0) {  // BVO[d] = bv·Wo[:,d] + bo[d]
      float acc = bo[lane];
#pragma unroll 8
      for (int t = 0; t < DD; ++t) acc = fmaf(bv[t], Wo[(size_t)t * DD + lane], acc);
      BVO[lane] = acc;
    }
  }
}

// ---------------- main: 256 threads, 4 nodes per block, 1 node per wave ----------------
// BYTE-IDENTICAL to round 8 (isolating the prep change).
__global__ __launch_bounds__(256, 5) void vc_main(
    const int* __restrict__ nodes, const int* __restrict__ hvc,
    const int* __restrict__ hr, const float* __restrict__ v2e,
    const char* __restrict__ ws, float* __restrict__ out, int N) {
  const unsigned short* __restrict__ H = (const unsigned short*)(ws + OFF_H);
  const unsigned short* __restrict__ M1T = (const unsigned short*)(ws + OFF_M1T);
  const unsigned short* __restrict__ WVOT = (const unsigned short*)(ws + OFF_WVOT);
  const float* __restrict__ BKQ = (const float*)(ws + OFF_BKQ);
  const float* __restrict__ BVO = (const float*)(ws + OFF_BVO);

  __shared__ __align__(16) char smem[25600 + 1088 + 1088];
  char* HlB = smem;                          // 4 waves x 50 rows x 128B, swizzled
  float* gS = (float*)(smem + 25600);        // [4][68] f32
  float* ctxS = (float*)(smem + 25600 + 1088);  // [4][68] f32

  const int tid = threadIdx.x;
  const int wid = tid >> 6;    // 0..3  (= node within block, = d-quarter n0)
  const int lane = tid & 63;
  const int kg = lane >> 4;    // 0..3
  const int rw = lane & 15;    // 0..15
  const int nb = blockIdx.x * 4;
  const int n = min(nb + wid, N - 1);

  // ---- history indices: lane l <-> slot l ----
  const int lidx = (lane < LL) ? lane : 0;
  const int idx = hvc[(size_t)n * LL + lidx] * NRAT + hr[(size_t)n * LL + lidx];

  // ---- async stage: 7 x global_load_lds, each = 8 rows (64 lanes x 16B) ----
  {
    const int chunk = lane & 7;
    char* wbase = HlB + wid * 6400;
#pragma unroll
    for (int i = 0; i < 7; ++i) {
      const int s = (i < 6) ? (i * 8 + (lane >> 3)) : (42 + (lane >> 3));
      const int sidx = __shfl(idx, s, 64);
      const char* src = (const char*)H + (size_t)sidx * 128 + ((chunk ^ (s & 7)) << 4);
      __builtin_amdgcn_global_load_lds(
          (const __attribute__((address_space(1))) void*)src,
          (__attribute__((address_space(3))) void*)(wbase + ((i < 6) ? i * 1024 : 5376)),
          16, 0, 0);
    }
  }

  // ---- G = X @ M1 + bkq : wave wid computes d-quarter n0==wid for the 4 nodes ----
  {
    const int node_id = nodes[min(nb + (rw & 3), N - 1)];
    const float* __restrict__ xrow = v2e + (size_t)node_id * DD;
    short8 xa[2];
#pragma unroll
    for (int ks = 0; ks < 2; ++ks) {
      const float4 f0 = *(const float4*)(xrow + ks * 32 + kg * 8);
      const float4 f1 = *(const float4*)(xrow + ks * 32 + kg * 8 + 4);
      U4S8 t;
      t.u4.x = pk2bf(f0.x, f0.y); t.u4.y = pk2bf(f0.z, f0.w);
      t.u4.z = pk2bf(f1.x, f1.y); t.u4.w = pk2bf(f1.z, f1.w);
      xa[ks] = t.s8;
    }
    const int n0 = wid;
    f32x4 a = {0.f, 0.f, 0.f, 0.f};
#pragma unroll
    for (int ks = 0; ks < 2; ++ks) {
      const short8 bf = *(const short8*)(M1T + (n0 * 16 + rw) * DD + ks * 32 + kg * 8);
      a = __builtin_amdgcn_mfma_f32_16x16x32_bf16(xa[ks], bf, a, 0, 0, 0);
    }
    if (kg == 0) {   // C rows 0..3 = nodes 0..3
      const float bkqv = BKQ[n0 * 16 + rw];
#pragma unroll
      for (int r = 0; r < 4; ++r) gS[r * 68 + n0 * 16 + rw] = a[r] + bkqv;
    }
  }
  __syncthreads();
  asm volatile("s_waitcnt vmcnt(0)" ::: "memory");  // H-stage complete
  __builtin_amdgcn_sched_barrier(0);

  const unsigned short* __restrict__ wH = (const unsigned short*)(HlB + wid * 6400);

  // ---- scores via MFMA from LDS ----
  short8 ga[2];
#pragma unroll
  for (int ks = 0; ks < 2; ++ks) {
    const float* __restrict__ gp = gS + wid * 68 + ks * 32 + kg * 8;
    const float4 f0 = *(const float4*)(gp);
    const float4 f1 = *(const float4*)(gp + 4);
    U4S8 t;
    t.u4.x = pk2bf(f0.x, f0.y); t.u4.y = pk2bf(f0.z, f0.w);
    t.u4.z = pk2bf(f1.x, f1.y); t.u4.w = pk2bf(f1.z, f1.w);
    ga[ks] = t.s8;
  }
  float s0, s1, s2, s3;
  {
    f32x4 a;
#pragma unroll
    for (int lt = 0; lt < 4; ++lt) {
      const int s = lt * 16 + rw;
      a = (f32x4){0.f, 0.f, 0.f, 0.f};
#pragma unroll
      for (int ks = 0; ks < 2; ++ks) {
        const int c = (ks * 4 + kg) ^ (s & 7);
        U4S8 hb;
        hb.u4 = *(const uint4*)(wH + s * 64 + c * 8);
        a = __builtin_amdgcn_mfma_f32_16x16x32_bf16(ga[ks], hb.s8, a, 0, 0, 0);
      }
      if (lt == 0) s0 = a[0];
      else if (lt == 1) s1 = a[0];
      else if (lt == 2) s2 = a[0];
      else s3 = a[0];
    }
  }
  s0 *= 0.125f; s1 *= 0.125f; s2 *= 0.125f;
  s3 = (rw < 2) ? s3 * 0.125f : -INFINITY;

  // ---- softmax over 50 slots ----
  float m = fmaxf(fmaxf(s0, s1), fmaxf(s2, s3));
#pragma unroll
  for (int x = 1; x <= 8; x <<= 1) m = fmaxf(m, __shfl_xor(m, x, 64));
  float e0 = __expf(s0 - m), e1 = __expf(s1 - m), e2 = __expf(s2 - m);
  float e3 = (rw < 2) ? __expf(s3 - m) : 0.f;
  float Z = ((e0 + e1) + (e2 + e3));
#pragma unroll
  for (int x = 1; x <= 8; x <<= 1) Z += __shfl_xor(Z, x, 64);
  const float invZ = 1.f / Z;

  // ---- ctx[d=lane] = sum_l e_l * H[slot l][d] / Z, all from LDS ----
  {
    const int sub = (lane & 7) * 2;
    const int hi3 = lane >> 3;
    float c0 = 0.f, c1 = 0.f;
#define CTX_BLOCK(EREG, BASE, CNT, CACC)                                        \
    _Pragma("unroll")                                                           \
    for (int j = 0; j < (CNT); ++j) {                                           \
      const int l = (BASE) + j;                                                 \
      const unsigned short hbb = *(const unsigned short*)(                      \
          (const char*)wH + l * 128 + (((hi3 ^ (l & 7)) << 4) | sub));          \
      CACC = fmaf(__uint_as_float(((unsigned int)hbb) << 16),                   \
                  rlanef(EREG, j), CACC);                                       \
    }
    CTX_BLOCK(e0, 0, 16, c0)
    CTX_BLOCK(e1, 16, 16, c1)
    CTX_BLOCK(e2, 32, 16, c0)
    CTX_BLOCK(e3, 48, 2, c1)
#undef CTX_BLOCK
    ctxS[wid * 68 + lane] = (c0 + c1) * invZ;
  }
  __syncthreads();

  // ---- OUT = CTX @ Wvo + bvo : wave wid computes d-quarter n0==wid ----
  {
    short8 ca[2];
#pragma unroll
    for (int ks = 0; ks < 2; ++ks) {
      const float* __restrict__ cp = ctxS + (rw & 3) * 68 + ks * 32 + kg * 8;
      const float4 f0 = *(const float4*)(cp);
      const float4 f1 = *(const float4*)(cp + 4);
      U4S8 t;
      t.u4.x = pk2bf(f0.x, f0.y); t.u4.y = pk2bf(f0.z, f0.w);
      t.u4.z = pk2bf(f1.x, f1.y); t.u4.w = pk2bf(f1.z, f1.w);
      ca[ks] = t.s8;
    }
    const int n0 = wid;
    f32x4 a = {0.f, 0.f, 0.f, 0.f};
#pragma unroll
    for (int ks = 0; ks < 2; ++ks) {
      const short8 bf = *(const short8*)(WVOT + (n0 * 16 + rw) * DD + ks * 32 + kg * 8);
      a = __builtin_amdgcn_mfma_f32_16x16x32_bf16(ca[ks], bf, a, 0, 0, 0);
    }
    if (kg == 0) {
      const float bvov = BVO[n0 * 16 + rw];
#pragma unroll
      for (int r = 0; r < 4; ++r) {
        const int node = nb + r;
        if (node < N) out[(size_t)node * DD + n0 * 16 + rw] = a[r] + bvov;
      }
    }
  }
}

extern "C" void kernel_launch(void* const* d_in, const int* in_sizes, int n_in,
                              void* d_out, int out_size, void* d_ws, size_t ws_size,
                              hipStream_t stream) {
  const int* nodes = (const int*)d_in[0];
  const int* hvc = (const int*)d_in[1];
  const int* hr = (const int*)d_in[2];
  const float* c2e = (const float*)d_in[3];
  const float* v2e = (const float*)d_in[4];
  const float* r2e = (const float*)d_in[5];
  const float* W1 = (const float*)d_in[6];
  const float* b1 = (const float*)d_in[7];
  const float* Wq = (const float*)d_in[8];
  const float* bq = (const float*)d_in[9];
  const float* Wk = (const float*)d_in[10];
  const float* bk = (const float*)d_in[11];  // unused: q·bk cancels in softmax
  const float* Wv = (const float*)d_in[12];
  const float* bv = (const float*)d_in[13];
  const float* Wo = (const float*)d_in[14];
  const float* bo = (const float*)d_in[15];
  (void)bk;
  float* out = (float*)d_out;
  char* ws = (char*)d_ws;

  const int N = in_sizes[0];

  prep_fast<<<65, 256, 0, stream>>>(c2e, r2e, W1, b1, Wq, bq, Wk, Wv, Wo, bv, bo, ws);
  vc_main<<<(N + 3) / 4, 256, 0, stream>>>(nodes, hvc, hr, v2e, ws, out, N);
}